// Round 1
// baseline (2237.260 us; speedup 1.0000x reference)
//
#include <hip/hip_runtime.h>

#define DD 128
#define HH 15

// ---------------- degree + dinv ----------------

__global__ void degree_kernel(const int* __restrict__ col, int* __restrict__ deg,
                              int E, int N) {
    int e = blockIdx.x * 256 + threadIdx.x;
    if (e < E) {
        int c = col[e];
        if ((unsigned)c < (unsigned)N) atomicAdd(&deg[c], 1);
    }
}

__global__ void dinv_kernel(const int* __restrict__ deg, float* __restrict__ dinv, int N) {
    int i = blockIdx.x * 256 + threadIdx.x;
    if (i < N) dinv[i] = 1.0f / sqrtf((float)(deg[i] + 1));  // +1 self-loop
}

// ---------------- layer 1 GEMM: h = x @ W1, agg = dinv^2 * h ----------------
// 16 nodes per 256-thread block; 16 threads per node (feature f = tid&15, f<15 active).

__global__ void gemm1_kernel(const float* __restrict__ x, const float* __restrict__ W,
                             const float* __restrict__ dinv,
                             float* __restrict__ h, float* __restrict__ agg) {
    __shared__ float Wl[DD * HH];    // 1920 floats
    __shared__ float xs[16 * DD];    // 2048 floats
    int tid = threadIdx.x;
    for (int i = tid; i < DD * HH; i += 256) Wl[i] = W[i];
    size_t base = (size_t)blockIdx.x * 16 * DD;
    const float4* xv = (const float4*)(x + base);
    float4* xsv = (float4*)xs;
    xsv[tid]        = xv[tid];        // 512 float4 total
    xsv[tid + 256]  = xv[tid + 256];
    __syncthreads();
    int g = tid >> 4, f = tid & 15;
    int n = blockIdx.x * 16 + g;
    if (f < HH) {
        const float* xrow = xs + g * DD;
        float acc = 0.f;
#pragma unroll 8
        for (int k = 0; k < DD; ++k) acc += xrow[k] * Wl[k * HH + f];
        float dv = dinv[n];
        h[(size_t)n * HH + f]   = acc;
        agg[(size_t)n * HH + f] = dv * dv * acc;   // self-loop contribution
    }
}

// ---------------- mid layers: in = relu(agg_in + b), h = in @ W, agg_out = dinv^2*h ----

__global__ void gemm_mid_kernel(const float* __restrict__ agg_in, const float* __restrict__ bias,
                                const float* __restrict__ W, const float* __restrict__ dinv,
                                float* __restrict__ h, float* __restrict__ agg_out) {
    __shared__ float Wl[HH * HH];     // 225
    __shared__ float s_in[16 * HH];   // 240
    int tid = threadIdx.x;
    if (tid < HH * HH) Wl[tid] = W[tid];
    int n0 = blockIdx.x * 16;
    if (tid < 16 * HH) {
        float v = agg_in[(size_t)n0 * HH + tid] + bias[tid % HH];
        s_in[tid] = v > 0.f ? v : 0.f;
    }
    __syncthreads();
    int g = tid >> 4, f = tid & 15;
    int n = n0 + g;
    if (f < HH) {
        const float* in = s_in + g * HH;
        float acc = 0.f;
#pragma unroll
        for (int k = 0; k < HH; ++k) acc += in[k] * Wl[k * HH + f];
        float dv = dinv[n];
        h[(size_t)n * HH + f]       = acc;
        agg_out[(size_t)n * HH + f] = dv * dv * acc;
    }
}

// ---------------- edge scatter: agg[col] += h[row] * dinv[row]*dinv[col] -------------
// 16 threads per edge (f = t&15, f<15 active).

__global__ void scatter_kernel(const int* __restrict__ row, const int* __restrict__ col,
                               const float* __restrict__ dinv, const float* __restrict__ h,
                               float* __restrict__ agg, int E, int N) {
    long long t = (long long)blockIdx.x * 256 + threadIdx.x;
    int e = (int)(t >> 4);
    int f = (int)(t & 15);
    if (e >= E || f >= HH) return;
    int r = row[e], c = col[e];
    if ((unsigned)r >= (unsigned)N || (unsigned)c >= (unsigned)N) return;
    float norm = dinv[r] * dinv[c];
    atomicAdd(&agg[(size_t)c * HH + f], h[(size_t)r * HH + f] * norm);
}

// ---------------- output GEMM: out = relu(agg + b3) @ Wc + bc ----------------
// 2 nodes per 256-thread block, 128 threads (features) per node.

__global__ void gemm_out_kernel(const float* __restrict__ agg_in, const float* __restrict__ bias,
                                const float* __restrict__ Wc, const float* __restrict__ bc,
                                float* __restrict__ out) {
    __shared__ float Wl[HH * DD];    // 1920
    __shared__ float s_in[2 * HH];   // 30
    int tid = threadIdx.x;
    for (int i = tid; i < HH * DD; i += 256) Wl[i] = Wc[i];
    int n0 = blockIdx.x * 2;
    if (tid < 2 * HH) {
        float v = agg_in[(size_t)n0 * HH + tid] + bias[tid % HH];
        s_in[tid] = v > 0.f ? v : 0.f;
    }
    __syncthreads();
    int g = tid >> 7, f = tid & 127;
    int n = n0 + g;
    const float* in = s_in + g * HH;
    float acc = bc[f];
#pragma unroll
    for (int k = 0; k < HH; ++k) acc += in[k] * Wl[k * DD + f];
    out[(size_t)n * DD + f] = acc;
}

// ---------------- launch ----------------

extern "C" void kernel_launch(void* const* d_in, const int* in_sizes, int n_in,
                              void* d_out, int out_size, void* d_ws, size_t ws_size,
                              hipStream_t stream) {
    const float* x  = (const float*)d_in[0];
    const int*   ei = (const int*)d_in[1];
    const float* W1 = (const float*)d_in[2];
    const float* b1 = (const float*)d_in[3];
    const float* W2 = (const float*)d_in[4];
    const float* b2 = (const float*)d_in[5];
    const float* W3 = (const float*)d_in[6];
    const float* b3 = (const float*)d_in[7];
    const float* Wc = (const float*)d_in[8];
    const float* bc = (const float*)d_in[9];
    float* out = (float*)d_out;

    int N = in_sizes[0] / DD;   // 100000
    int E = in_sizes[1] / 2;    // 6400000
    const int* row = ei;        // edge_index[0] = source
    const int* col = ei + E;    // edge_index[1] = target

    char* ws = (char*)d_ws;
    size_t off = 0;
    auto alloc = [&](size_t bytes) {
        void* p = ws + off;
        off += (bytes + 255) & ~(size_t)255;
        return p;
    };
    int*   deg  = (int*)  alloc((size_t)N * 4);
    float* dinv = (float*)alloc((size_t)N * 4);
    float* h    = (float*)alloc((size_t)N * HH * 4);
    float* aggA = (float*)alloc((size_t)N * HH * 4);
    float* aggB = (float*)alloc((size_t)N * HH * 4);
    (void)ws_size; (void)n_in; (void)out_size;

    hipMemsetAsync(deg, 0, (size_t)N * 4, stream);
    degree_kernel<<<(E + 255) / 256, 256, 0, stream>>>(col, deg, E, N);
    dinv_kernel<<<(N + 255) / 256, 256, 0, stream>>>(deg, dinv, N);

    int nb16 = (N + 15) / 16;                       // 6250 (exact)
    long long st = (long long)E * 16;
    int sblocks = (int)((st + 255) / 256);          // 400000 (exact)

    // layer 1
    gemm1_kernel<<<nb16, 256, 0, stream>>>(x, W1, dinv, h, aggA);
    scatter_kernel<<<sblocks, 256, 0, stream>>>(row, col, dinv, h, aggA, E, N);
    // layer 2
    gemm_mid_kernel<<<nb16, 256, 0, stream>>>(aggA, b1, W2, dinv, h, aggB);
    scatter_kernel<<<sblocks, 256, 0, stream>>>(row, col, dinv, h, aggB, E, N);
    // layer 3
    gemm_mid_kernel<<<nb16, 256, 0, stream>>>(aggB, b2, W3, dinv, h, aggA);
    scatter_kernel<<<sblocks, 256, 0, stream>>>(row, col, dinv, h, aggA, E, N);
    // output
    gemm_out_kernel<<<(N + 1) / 2, 256, 0, stream>>>(aggA, b3, Wc, bc, out);
}

// Round 2
// 1411.808 us; speedup vs baseline: 1.5847x; 1.5847x over previous
//
#include <hip/hip_runtime.h>

#define DD 128
#define HH 15

// ---------------- degree + dinv ----------------

__global__ void degree_kernel(const int* __restrict__ col, int* __restrict__ deg,
                              int E, int N) {
    int e = blockIdx.x * 256 + threadIdx.x;
    if (e < E) {
        int c = col[e];
        if ((unsigned)c < (unsigned)N) atomicAdd(&deg[c], 1);
    }
}

__global__ void dinv_kernel(const int* __restrict__ deg, float* __restrict__ dinv, int N) {
    int i = blockIdx.x * 256 + threadIdx.x;
    if (i < N) dinv[i] = 1.0f / sqrtf((float)(deg[i] + 1));  // +1 self-loop
}

// ---------------- exclusive scan of deg -> rowptr (3-kernel hierarchical) ----------

__global__ void scan_block(const int* __restrict__ deg, int* __restrict__ rowptr,
                           int* __restrict__ bsum, int N) {
    __shared__ int sh[256];
    int i = blockIdx.x * 256 + threadIdx.x;
    int v = (i < N) ? deg[i] : 0;
    sh[threadIdx.x] = v;
    __syncthreads();
    for (int off = 1; off < 256; off <<= 1) {
        int t = (threadIdx.x >= off) ? sh[threadIdx.x - off] : 0;
        __syncthreads();
        sh[threadIdx.x] += t;
        __syncthreads();
    }
    if (i < N) rowptr[i] = sh[threadIdx.x] - v;   // exclusive
    if (threadIdx.x == 255) bsum[blockIdx.x] = sh[255];
}

__global__ void scan_bsum(int* __restrict__ bsum, int NB) {
    __shared__ int sh[512];
    int t = threadIdx.x;
    int v = (t < NB) ? bsum[t] : 0;
    sh[t] = v;
    __syncthreads();
    for (int off = 1; off < 512; off <<= 1) {
        int x = (t >= off) ? sh[t - off] : 0;
        __syncthreads();
        sh[t] += x;
        __syncthreads();
    }
    if (t < NB) bsum[t] = sh[t] - v;              // exclusive
}

__global__ void scan_add(int* __restrict__ rowptr, const int* __restrict__ bsum,
                         int* __restrict__ cursor, int N, int E) {
    int i = blockIdx.x * 256 + threadIdx.x;
    if (i < N) {
        int v = rowptr[i] + bsum[i >> 8];
        rowptr[i] = v;
        cursor[i] = v;
    }
    if (i == N) rowptr[N] = E;
}

// ---------------- CSR fill (counting-sort scatter) ----------------

__global__ void csr_fill(const int* __restrict__ row, const int* __restrict__ col,
                         int* __restrict__ cursor, int* __restrict__ csr_row, int E, int N) {
    int e = blockIdx.x * 256 + threadIdx.x;
    if (e < E) {
        int c = col[e];
        if ((unsigned)c < (unsigned)N) {
            int p = atomicAdd(&cursor[c], 1);
            csr_row[p] = row[e];
        }
    }
}

// ---------------- layer 1 GEMM: hs = (x @ W1) * dinv ----------------

__global__ void gemm1_kernel(const float* __restrict__ x, const float* __restrict__ W,
                             const float* __restrict__ dinv, float* __restrict__ hs) {
    __shared__ float Wl[DD * HH];    // 1920 floats
    __shared__ float xs[16 * DD];    // 2048 floats
    int tid = threadIdx.x;
    for (int i = tid; i < DD * HH; i += 256) Wl[i] = W[i];
    size_t base = (size_t)blockIdx.x * 16 * DD;
    const float4* xv = (const float4*)(x + base);
    float4* xsv = (float4*)xs;
    xsv[tid]       = xv[tid];
    xsv[tid + 256] = xv[tid + 256];
    __syncthreads();
    int g = tid >> 4, f = tid & 15;
    int n = blockIdx.x * 16 + g;
    if (f < HH) {
        const float* xrow = xs + g * DD;
        float acc = 0.f;
#pragma unroll 8
        for (int k = 0; k < DD; ++k) acc += xrow[k] * Wl[k * HH + f];
        hs[(size_t)n * HH + f] = acc * dinv[n];
    }
}

// ---------------- mid layers: in = relu(agg + b), hs' = (in @ W) * dinv ----------

__global__ void gemm_mid_kernel(const float* __restrict__ agg_in, const float* __restrict__ bias,
                                const float* __restrict__ W, const float* __restrict__ dinv,
                                float* __restrict__ hs) {
    __shared__ float Wl[HH * HH];     // 225
    __shared__ float s_in[16 * HH];   // 240
    int tid = threadIdx.x;
    if (tid < HH * HH) Wl[tid] = W[tid];
    int n0 = blockIdx.x * 16;
    if (tid < 16 * HH) {
        float v = agg_in[(size_t)n0 * HH + tid] + bias[tid % HH];
        s_in[tid] = v > 0.f ? v : 0.f;
    }
    __syncthreads();
    int g = tid >> 4, f = tid & 15;
    int n = n0 + g;
    if (f < HH) {
        const float* in = s_in + g * HH;
        float acc = 0.f;
#pragma unroll
        for (int k = 0; k < HH; ++k) acc += in[k] * Wl[k * HH + f];
        hs[(size_t)n * HH + f] = acc * dinv[n];
    }
}

// ---------------- gather aggregation: agg[c] = dinv[c] * (hs[c] + sum hs[row]) --------
// One wave (64 lanes) per node: 4 edge-groups x 16 lanes (feature = lane&15).

__global__ void aggregate_kernel(const int* __restrict__ rowptr, const int* __restrict__ csr_row,
                                 const float* __restrict__ dinv, const float* __restrict__ hs,
                                 float* __restrict__ agg, int N) {
    int wave = (blockIdx.x * 256 + threadIdx.x) >> 6;
    int lane = threadIdx.x & 63;
    if (wave >= N) return;
    int c = wave;
    int s = rowptr[c], epe = rowptr[c + 1];
    int f = lane & 15;
    int g = lane >> 4;                 // 0..3
    float acc = 0.f;
    if (f < HH) {
        for (int e = s + g; e < epe; e += 4) {
            int r = csr_row[e];
            acc += hs[(size_t)r * HH + f];
        }
    }
    acc += __shfl_down(acc, 32, 64);
    acc += __shfl_down(acc, 16, 64);
    if (lane < HH) {
        float d = dinv[c];
        agg[(size_t)c * HH + lane] = d * (acc + hs[(size_t)c * HH + lane]);
    }
}

// ---------------- output GEMM: out = relu(agg + b3) @ Wc + bc ----------------

__global__ void gemm_out_kernel(const float* __restrict__ agg_in, const float* __restrict__ bias,
                                const float* __restrict__ Wc, const float* __restrict__ bc,
                                float* __restrict__ out) {
    __shared__ float Wl[HH * DD];    // 1920
    __shared__ float s_in[2 * HH];   // 30
    int tid = threadIdx.x;
    for (int i = tid; i < HH * DD; i += 256) Wl[i] = Wc[i];
    int n0 = blockIdx.x * 2;
    if (tid < 2 * HH) {
        float v = agg_in[(size_t)n0 * HH + tid] + bias[tid % HH];
        s_in[tid] = v > 0.f ? v : 0.f;
    }
    __syncthreads();
    int g = tid >> 7, f = tid & 127;
    int n = n0 + g;
    const float* in = s_in + g * HH;
    float acc = bc[f];
#pragma unroll
    for (int k = 0; k < HH; ++k) acc += in[k] * Wl[k * DD + f];
    out[(size_t)n * DD + f] = acc;
}

// ---------------- launch ----------------

extern "C" void kernel_launch(void* const* d_in, const int* in_sizes, int n_in,
                              void* d_out, int out_size, void* d_ws, size_t ws_size,
                              hipStream_t stream) {
    const float* x  = (const float*)d_in[0];
    const int*   ei = (const int*)d_in[1];
    const float* W1 = (const float*)d_in[2];
    const float* b1 = (const float*)d_in[3];
    const float* W2 = (const float*)d_in[4];
    const float* b2 = (const float*)d_in[5];
    const float* W3 = (const float*)d_in[6];
    const float* b3 = (const float*)d_in[7];
    const float* Wc = (const float*)d_in[8];
    const float* bc = (const float*)d_in[9];
    float* out = (float*)d_out;

    int N = in_sizes[0] / DD;   // 100000
    int E = in_sizes[1] / 2;    // 6400000
    const int* row = ei;        // edge_index[0] = source
    const int* col = ei + E;    // edge_index[1] = target

    char* ws = (char*)d_ws;
    size_t off = 0;
    auto alloc = [&](size_t bytes) {
        void* p = ws + off;
        off += (bytes + 255) & ~(size_t)255;
        return p;
    };
    int NB = (N + 255) / 256;                       // 391 scan blocks
    int*   deg     = (int*)  alloc((size_t)N * 4);
    float* dinv    = (float*)alloc((size_t)N * 4);
    int*   rowptr  = (int*)  alloc((size_t)(N + 1) * 4);
    int*   cursor  = (int*)  alloc((size_t)N * 4);
    int*   bsum    = (int*)  alloc((size_t)NB * 4);
    int*   csr_row = (int*)  alloc((size_t)E * 4);  // 25.6 MB
    float* hsBuf   = (float*)alloc((size_t)N * HH * 4);
    float* aggBuf  = (float*)alloc((size_t)N * HH * 4);
    (void)ws_size; (void)n_in; (void)out_size;

    // graph structure (norm + CSR) — rebuilt every call, no persistent state
    hipMemsetAsync(deg, 0, (size_t)N * 4, stream);
    degree_kernel<<<(E + 255) / 256, 256, 0, stream>>>(col, deg, E, N);
    dinv_kernel<<<(N + 255) / 256, 256, 0, stream>>>(deg, dinv, N);
    scan_block<<<NB, 256, 0, stream>>>(deg, rowptr, bsum, N);
    scan_bsum<<<1, 512, 0, stream>>>(bsum, NB);
    scan_add<<<(N + 256) / 256, 256, 0, stream>>>(rowptr, bsum, cursor, N, E);
    csr_fill<<<(E + 255) / 256, 256, 0, stream>>>(row, col, cursor, csr_row, E, N);

    int nb16 = (N + 15) / 16;                       // 6250
    int agg_blocks = (N + 3) / 4;                   // one wave per node, 4 nodes/block

    // layer 1
    gemm1_kernel<<<nb16, 256, 0, stream>>>(x, W1, dinv, hsBuf);
    aggregate_kernel<<<agg_blocks, 256, 0, stream>>>(rowptr, csr_row, dinv, hsBuf, aggBuf, N);
    // layer 2
    gemm_mid_kernel<<<nb16, 256, 0, stream>>>(aggBuf, b1, W2, dinv, hsBuf);
    aggregate_kernel<<<agg_blocks, 256, 0, stream>>>(rowptr, csr_row, dinv, hsBuf, aggBuf, N);
    // layer 3
    gemm_mid_kernel<<<nb16, 256, 0, stream>>>(aggBuf, b2, W3, dinv, hsBuf);
    aggregate_kernel<<<agg_blocks, 256, 0, stream>>>(rowptr, csr_row, dinv, hsBuf, aggBuf, N);
    // output
    gemm_out_kernel<<<(N + 1) / 2, 256, 0, stream>>>(aggBuf, b3, Wc, bc, out);
}

// Round 3
// 1103.268 us; speedup vs baseline: 2.0278x; 1.2797x over previous
//
#include <hip/hip_runtime.h>

#define DD 128
#define HH 15
#define BSHIFT 9                 // 512 nodes per bucket
#define BHALF 98                 // buckets per pass (2 passes)
#define CHUNK 4096               // edges per partA block

// ---------------- degree + dinv ----------------

__global__ void degree_kernel(const int* __restrict__ col, int* __restrict__ deg,
                              int E, int N) {
    int e = blockIdx.x * 256 + threadIdx.x;
    if (e < E) {
        int c = col[e];
        if ((unsigned)c < (unsigned)N) atomicAdd(&deg[c], 1);
    }
}

__global__ void dinv_kernel(const int* __restrict__ deg, float* __restrict__ dinv, int N) {
    int i = blockIdx.x * 256 + threadIdx.x;
    if (i < N) dinv[i] = 1.0f / sqrtf((float)(deg[i] + 1));  // +1 self-loop
}

// ---------------- exclusive scan of deg -> rowptr ----------------

__global__ void scan_block(const int* __restrict__ deg, int* __restrict__ rowptr,
                           int* __restrict__ bsum, int N) {
    __shared__ int sh[256];
    int i = blockIdx.x * 256 + threadIdx.x;
    int v = (i < N) ? deg[i] : 0;
    sh[threadIdx.x] = v;
    __syncthreads();
    for (int off = 1; off < 256; off <<= 1) {
        int t = (threadIdx.x >= off) ? sh[threadIdx.x - off] : 0;
        __syncthreads();
        sh[threadIdx.x] += t;
        __syncthreads();
    }
    if (i < N) rowptr[i] = sh[threadIdx.x] - v;   // exclusive
    if (threadIdx.x == 255) bsum[blockIdx.x] = sh[255];
}

__global__ void scan_bsum(int* __restrict__ bsum, int NB) {
    __shared__ int sh[512];
    int t = threadIdx.x;
    int v = (t < NB) ? bsum[t] : 0;
    sh[t] = v;
    __syncthreads();
    for (int off = 1; off < 512; off <<= 1) {
        int x = (t >= off) ? sh[t - off] : 0;
        __syncthreads();
        sh[t] += x;
        __syncthreads();
    }
    if (t < NB) bsum[t] = sh[t] - v;              // exclusive
}

__global__ void scan_add(int* __restrict__ rowptr, const int* __restrict__ bsum,
                         int N, int E) {
    int i = blockIdx.x * 256 + threadIdx.x;
    if (i < N) rowptr[i] += bsum[i >> 8];
    if (i == N) rowptr[N] = E;
}

// ---------------- CSR build, phase A: LDS-staged bucket binning ----------------
// pack = row (17b) | local_col (9b) << 17

__global__ void partA(const int* __restrict__ row, const int* __restrict__ col,
                      int* __restrict__ gcur, unsigned* __restrict__ tmp,
                      int E, int b0, int b1) {
    __shared__ int histo[BHALF];
    __shared__ int hbase[BHALF];
    __shared__ int hscan[BHALF];
    __shared__ int scanT[256];
    __shared__ int s_total;
    __shared__ unsigned staged[CHUNK];
    __shared__ int saddr[CHUNK];
    int tid = threadIdx.x;
    int start = blockIdx.x * CHUNK;
    for (int i = tid; i < BHALF; i += 256) histo[i] = 0;
    __syncthreads();
    unsigned pk[16]; unsigned short lp[16]; unsigned char bk[16];
    for (int k = 0; k < 16; ++k) {
        int e = start + k * 256 + tid;
        bk[k] = 0xFF;
        if (e < E) {
            int cc = col[e];
            int b = cc >> BSHIFT;
            if (b >= b0 && b < b1) {
                int rr = row[e];
                pk[k] = (unsigned)rr | ((unsigned)(cc & ((1 << BSHIFT) - 1)) << 17);
                bk[k] = (unsigned char)(b - b0);
                lp[k] = (unsigned short)atomicAdd(&histo[b - b0], 1);
            }
        }
    }
    __syncthreads();
    int v = (tid < BHALF) ? histo[tid] : 0;
    scanT[tid] = v;
    __syncthreads();
    for (int off = 1; off < 256; off <<= 1) {
        int t2 = (tid >= off) ? scanT[tid - off] : 0;
        __syncthreads();
        scanT[tid] += t2;
        __syncthreads();
    }
    if (tid == 255) s_total = scanT[255];
    if (tid < BHALF) {
        hscan[tid] = scanT[tid] - v;                       // chunk-local exclusive
        if (v > 0) hbase[tid] = atomicAdd(&gcur[tid], v);  // reserve global run
    }
    __syncthreads();
    for (int k = 0; k < 16; ++k) {
        if (bk[k] != 0xFF) {
            int b = bk[k];
            int slot = hscan[b] + lp[k];
            staged[slot] = pk[k];
            saddr[slot]  = hbase[b] + lp[k];
        }
    }
    __syncthreads();
    int tot = s_total;
    for (int k = tid; k < tot; k += 256)
        tmp[saddr[k]] = staged[k];                         // bucket-contiguous runs
}

__global__ void init_gcur(const int* __restrict__ rowptr, int* __restrict__ gcur,
                          int b0, int nb) {
    int i = threadIdx.x;
    if (i < nb) gcur[i] = rowptr[(b0 + i) << BSHIFT] - rowptr[b0 << BSHIFT];
}

// ---------------- CSR build, phase B: per-bucket counting sort (LDS cursors) ----

__global__ void partB(const int* __restrict__ rowptr, const unsigned* __restrict__ tmp,
                      int* __restrict__ csr_row, int N, int b0) {
    __shared__ int cur[1 << BSHIFT];
    int b = b0 + blockIdx.x;
    int node0 = b << BSHIFT;
    int nn = min(1 << BSHIFT, N - node0);
    int tid = threadIdx.x;
    for (int i = tid; i < nn; i += 1024) cur[i] = rowptr[node0 + i];
    __syncthreads();
    int base = rowptr[b0 << BSHIFT];
    int s = rowptr[node0];
    int epe = rowptr[min(node0 + (1 << BSHIFT), N)];
    for (int e = s + tid; e < epe; e += 1024) {
        unsigned v = tmp[e - base];
        int lc = (int)(v >> 17);
        int pos = atomicAdd(&cur[lc], 1);
        csr_row[pos] = (int)(v & 0x1FFFFu);    // window ~130KB -> L2-absorbed
    }
}

// ---------------- layer 1 GEMM: hs = (x @ W1) * dinv  (stride-16 output) --------

__global__ void gemm1_kernel(const float* __restrict__ x, const float* __restrict__ W,
                             const float* __restrict__ dinv, float* __restrict__ hs) {
    __shared__ float Wl[DD * HH];
    __shared__ float xs[16 * DD];
    int tid = threadIdx.x;
    for (int i = tid; i < DD * HH; i += 256) Wl[i] = W[i];
    size_t base = (size_t)blockIdx.x * 16 * DD;
    const float4* xv = (const float4*)(x + base);
    float4* xsv = (float4*)xs;
    xsv[tid]       = xv[tid];
    xsv[tid + 256] = xv[tid + 256];
    __syncthreads();
    int g = tid >> 4, f = tid & 15;
    int n = blockIdx.x * 16 + g;
    if (f < HH) {
        const float* xrow = xs + g * DD;
        float acc = 0.f;
#pragma unroll 8
        for (int k = 0; k < DD; ++k) acc += xrow[k] * Wl[k * HH + f];
        hs[((size_t)n << 4) + f] = acc * dinv[n];
    }
}

// ---------------- mid layers: in = relu(agg + b), hs' = (in @ W) * dinv ----------

__global__ void gemm_mid_kernel(const float* __restrict__ agg_in, const float* __restrict__ bias,
                                const float* __restrict__ W, const float* __restrict__ dinv,
                                float* __restrict__ hs) {
    __shared__ float Wl[HH * HH];
    __shared__ float s_in[256];          // 16 nodes x stride 16
    int tid = threadIdx.x;
    if (tid < HH * HH) Wl[tid] = W[tid];
    int n0 = blockIdx.x * 16;
    int g = tid >> 4, f = tid & 15;
    if (f < HH) {
        float v = agg_in[((size_t)(n0 + g) << 4) + f] + bias[f];
        s_in[tid] = v > 0.f ? v : 0.f;
    }
    __syncthreads();
    int n = n0 + g;
    if (f < HH) {
        const float* in = s_in + g * 16;
        float acc = 0.f;
#pragma unroll
        for (int k = 0; k < HH; ++k) acc += in[k] * Wl[k * HH + f];
        hs[((size_t)n << 4) + f] = acc * dinv[n];
    }
}

// ---------------- gather aggregation: agg[c] = dinv[c]*(hs[c] + sum hs[row]) -----
// One wave per node; hs stride 16 -> each gather is exactly one 64B line.

__global__ void aggregate_kernel(const int* __restrict__ rowptr, const int* __restrict__ csr_row,
                                 const float* __restrict__ dinv, const float* __restrict__ hs,
                                 float* __restrict__ agg, int N) {
    int wave = (blockIdx.x * 256 + threadIdx.x) >> 6;
    int lane = threadIdx.x & 63;
    if (wave >= N) return;
    int c = wave;
    int s = rowptr[c], epe = rowptr[c + 1];
    int f = lane & 15;
    int g = lane >> 4;
    float acc = 0.f;
    for (int e = s + g; e < epe; e += 4) {
        int r = csr_row[e];
        acc += hs[((size_t)r << 4) + f];   // f==15 lanes read padding, never summed into f<15
    }
    acc += __shfl_down(acc, 32, 64);
    acc += __shfl_down(acc, 16, 64);
    if (lane < HH) {
        float d = dinv[c];
        agg[((size_t)c << 4) + lane] = d * (acc + hs[((size_t)c << 4) + lane]);
    }
}

// ---------------- output GEMM: out = relu(agg + b3) @ Wc + bc ----------------

__global__ void gemm_out_kernel(const float* __restrict__ agg_in, const float* __restrict__ bias,
                                const float* __restrict__ Wc, const float* __restrict__ bc,
                                float* __restrict__ out) {
    __shared__ float Wl[HH * DD];
    __shared__ float s_in[32];
    int tid = threadIdx.x;
    for (int i = tid; i < HH * DD; i += 256) Wl[i] = Wc[i];
    int n0 = blockIdx.x * 2;
    if (tid < 32) {
        int gg = tid >> 4, ff = tid & 15;
        float v = (ff < HH) ? agg_in[((size_t)(n0 + gg) << 4) + ff] + bias[ff] : 0.f;
        s_in[tid] = v > 0.f ? v : 0.f;
    }
    __syncthreads();
    int g = tid >> 7, f = tid & 127;
    int n = n0 + g;
    const float* in = s_in + g * 16;
    float acc = bc[f];
#pragma unroll
    for (int k = 0; k < HH; ++k) acc += in[k] * Wl[k * DD + f];
    out[(size_t)n * DD + f] = acc;
}

// ---------------- launch ----------------

extern "C" void kernel_launch(void* const* d_in, const int* in_sizes, int n_in,
                              void* d_out, int out_size, void* d_ws, size_t ws_size,
                              hipStream_t stream) {
    const float* x  = (const float*)d_in[0];
    const int*   ei = (const int*)d_in[1];
    const float* W1 = (const float*)d_in[2];
    const float* b1 = (const float*)d_in[3];
    const float* W2 = (const float*)d_in[4];
    const float* b2 = (const float*)d_in[5];
    const float* W3 = (const float*)d_in[6];
    const float* b3 = (const float*)d_in[7];
    const float* Wc = (const float*)d_in[8];
    const float* bc = (const float*)d_in[9];
    float* out = (float*)d_out;

    int N = in_sizes[0] / DD;   // 100000
    int E = in_sizes[1] / 2;    // 6400000
    const int* row = ei;        // edge_index[0] = source
    const int* col = ei + E;    // edge_index[1] = target

    char* ws = (char*)d_ws;
    size_t off = 0;
    auto alloc = [&](size_t bytes) {
        void* p = ws + off;
        off += (bytes + 255) & ~(size_t)255;
        return p;
    };
    int NB = (N + 255) / 256;                          // 391 scan blocks
    int nbuck = (N + (1 << BSHIFT) - 1) >> BSHIFT;     // 196
    int*      deg     = (int*)     alloc((size_t)N * 4);
    float*    dinv    = (float*)   alloc((size_t)N * 4);
    int*      rowptr  = (int*)     alloc((size_t)(N + 1) * 4);
    int*      bsum    = (int*)     alloc((size_t)NB * 4);
    int*      gcur    = (int*)     alloc((size_t)BHALF * 4);
    int*      csr_row = (int*)     alloc((size_t)E * 4);            // 25.6 MB
    unsigned* tmpHalf = (unsigned*)alloc((size_t)3400000 * 4);      // 13.6 MB, aliased below
    (void)ws_size; (void)n_in; (void)out_size;

    // hs/agg (stride-16, 6.4 MB each) alias tmpHalf — tmp is dead after partB.
    float* hsBuf  = (float*)tmpHalf;
    float* aggBuf = hsBuf + (size_t)N * 16;

    // norm + rowptr
    hipMemsetAsync(deg, 0, (size_t)N * 4, stream);
    degree_kernel<<<(E + 255) / 256, 256, 0, stream>>>(col, deg, E, N);
    dinv_kernel<<<(N + 255) / 256, 256, 0, stream>>>(deg, dinv, N);
    scan_block<<<NB, 256, 0, stream>>>(deg, rowptr, bsum, N);
    scan_bsum<<<1, 512, 0, stream>>>(bsum, NB);
    scan_add<<<(N + 256) / 256, 256, 0, stream>>>(rowptr, bsum, N, E);

    // CSR build: two half-passes (bounds tmp workspace)
    int ablocks = (E + CHUNK - 1) / CHUNK;             // 1563
    for (int pass = 0; pass < 2; ++pass) {
        int b0 = pass * BHALF;
        int b1 = min(b0 + BHALF, nbuck);
        init_gcur<<<1, 128, 0, stream>>>(rowptr, gcur, b0, b1 - b0);
        partA<<<ablocks, 256, 0, stream>>>(row, col, gcur, tmpHalf, E, b0, b1);
        partB<<<b1 - b0, 1024, 0, stream>>>(rowptr, tmpHalf, csr_row, N, b0);
    }

    int nb16 = (N + 15) / 16;                          // 6250
    int agg_blocks = (N + 3) / 4;                      // one wave per node

    // layer 1
    gemm1_kernel<<<nb16, 256, 0, stream>>>(x, W1, dinv, hsBuf);
    aggregate_kernel<<<agg_blocks, 256, 0, stream>>>(rowptr, csr_row, dinv, hsBuf, aggBuf, N);
    // layer 2
    gemm_mid_kernel<<<nb16, 256, 0, stream>>>(aggBuf, b1, W2, dinv, hsBuf);
    aggregate_kernel<<<agg_blocks, 256, 0, stream>>>(rowptr, csr_row, dinv, hsBuf, aggBuf, N);
    // layer 3
    gemm_mid_kernel<<<nb16, 256, 0, stream>>>(aggBuf, b2, W3, dinv, hsBuf);
    aggregate_kernel<<<agg_blocks, 256, 0, stream>>>(rowptr, csr_row, dinv, hsBuf, aggBuf, N);
    // output
    gemm_out_kernel<<<(N + 1) / 2, 256, 0, stream>>>(aggBuf, b3, Wc, bc, out);
}

// Round 4
// 657.137 us; speedup vs baseline: 3.4046x; 1.6789x over previous
//
#include <hip/hip_runtime.h>

#define DD 128
#define HH 15
#define BSHIFT 9                 // 512 nodes per bucket
#define NBUCK 196                // ceil(100000 / 512)
#define BHALF 98                 // buckets per pass (2 passes, bounds tmp size)
#define CHUNK 4096               // edges per partA block

// ---------------- bucket histogram (LDS, no global scatter atomics) ----------------

__global__ void bucket_count(const int* __restrict__ col, int* __restrict__ bcount, int E) {
    __shared__ int h[NBUCK];
    int tid = threadIdx.x;
    for (int i = tid; i < NBUCK; i += 256) h[i] = 0;
    __syncthreads();
    int start = blockIdx.x * CHUNK;
    for (int k = 0; k < 16; ++k) {
        int e = start + k * 256 + tid;
        if (e < E) atomicAdd(&h[col[e] >> BSHIFT], 1);   // LDS atomic
    }
    __syncthreads();
    for (int i = tid; i < NBUCK; i += 256)
        if (h[i]) atomicAdd(&bcount[i], h[i]);           // ~196 global adds/block
}

// scan 196 bucket counts -> bbase[197]; also rowptr[N] = E
__global__ void scan196(const int* __restrict__ bcount, int* __restrict__ bbase,
                        int* __restrict__ rowptr, int N, int E) {
    __shared__ int sh[256];
    int t = threadIdx.x;
    int v = (t < NBUCK) ? bcount[t] : 0;
    sh[t] = v;
    __syncthreads();
    for (int off = 1; off < 256; off <<= 1) {
        int x = (t >= off) ? sh[t - off] : 0;
        __syncthreads();
        sh[t] += x;
        __syncthreads();
    }
    if (t < NBUCK) bbase[t] = sh[t] - v;   // exclusive
    if (t == 0) { bbase[NBUCK] = E; rowptr[N] = E; }
}

__global__ void init_gcur(const int* __restrict__ bbase, int* __restrict__ gcur,
                          int b0, int nb) {
    int i = threadIdx.x;
    if (i < nb) gcur[i] = bbase[b0 + i] - bbase[b0];   // offset within tmpHalf
}

// ---------------- CSR build, phase A: LDS-staged bucket binning ----------------
// pack = row (17b) | local_col (9b) << 17

__global__ void partA(const int* __restrict__ row, const int* __restrict__ col,
                      int* __restrict__ gcur, unsigned* __restrict__ tmp,
                      int E, int b0, int b1) {
    __shared__ int histo[BHALF];
    __shared__ int hbase[BHALF];
    __shared__ int hscan[BHALF];
    __shared__ int scanT[256];
    __shared__ int s_total;
    __shared__ unsigned staged[CHUNK];
    __shared__ int saddr[CHUNK];
    int tid = threadIdx.x;
    int start = blockIdx.x * CHUNK;
    for (int i = tid; i < BHALF; i += 256) histo[i] = 0;
    __syncthreads();
    unsigned pk[16]; unsigned short lp[16]; unsigned char bk[16];
    for (int k = 0; k < 16; ++k) {
        int e = start + k * 256 + tid;
        bk[k] = 0xFF;
        if (e < E) {
            int cc = col[e];
            int b = cc >> BSHIFT;
            if (b >= b0 && b < b1) {
                int rr = row[e];
                pk[k] = (unsigned)rr | ((unsigned)(cc & ((1 << BSHIFT) - 1)) << 17);
                bk[k] = (unsigned char)(b - b0);
                lp[k] = (unsigned short)atomicAdd(&histo[b - b0], 1);
            }
        }
    }
    __syncthreads();
    int v = (tid < BHALF) ? histo[tid] : 0;
    scanT[tid] = v;
    __syncthreads();
    for (int off = 1; off < 256; off <<= 1) {
        int t2 = (tid >= off) ? scanT[tid - off] : 0;
        __syncthreads();
        scanT[tid] += t2;
        __syncthreads();
    }
    if (tid == 255) s_total = scanT[255];
    if (tid < BHALF) {
        hscan[tid] = scanT[tid] - v;                       // chunk-local exclusive
        if (v > 0) hbase[tid] = atomicAdd(&gcur[tid], v);  // reserve global run
    }
    __syncthreads();
    for (int k = 0; k < 16; ++k) {
        if (bk[k] != 0xFF) {
            int b = bk[k];
            int slot = hscan[b] + lp[k];
            staged[slot] = pk[k];
            saddr[slot]  = hbase[b] + lp[k];
        }
    }
    __syncthreads();
    int tot = s_total;
    for (int k = tid; k < tot; k += 256)
        tmp[saddr[k]] = staged[k];                         // bucket-contiguous runs
}

// ---------------- CSR build, phase B ----------------
// Per bucket: LDS degree histogram -> rowptr + dinv, then LDS-cursor scatter.

__global__ void partB(const int* __restrict__ bbase, const unsigned* __restrict__ tmp,
                      int* __restrict__ rowptr, float* __restrict__ dinv,
                      int* __restrict__ csr_row, int N, int b0) {
    __shared__ int hist[1 << BSHIFT];
    __shared__ int cur[1 << BSHIFT];
    int b = b0 + blockIdx.x;
    int node0 = b << BSHIFT;
    int nn = min(1 << BSHIFT, N - node0);
    int tid = threadIdx.x;
    for (int i = tid; i < (1 << BSHIFT); i += 1024) hist[i] = 0;
    __syncthreads();
    int base = bbase[b], end = bbase[b + 1];
    int lbase = bbase[b0];
    for (int e = base + tid; e < end; e += 1024)
        atomicAdd(&hist[tmp[e - lbase] >> 17], 1);         // LDS atomic
    __syncthreads();
    int d0 = (tid < (1 << BSHIFT)) ? hist[tid] : 0;
    // Hillis-Steele inclusive scan over 512 entries (threads 512..1023 idle but barrier)
    for (int off = 1; off < (1 << BSHIFT); off <<= 1) {
        int x = 0;
        if (tid < (1 << BSHIFT) && tid >= off) x = hist[tid - off];
        __syncthreads();
        if (tid < (1 << BSHIFT)) hist[tid] += x;
        __syncthreads();
    }
    if (tid < (1 << BSHIFT)) {
        int excl = hist[tid] - d0;
        cur[tid] = base + excl;
        if (tid < nn) {
            rowptr[node0 + tid] = base + excl;
            dinv[node0 + tid] = 1.0f / sqrtf((float)(d0 + 1));   // +1 self-loop
        }
    }
    __syncthreads();
    for (int e = base + tid; e < end; e += 1024) {
        unsigned v = tmp[e - lbase];
        int lc = (int)(v >> 17);
        int pos = atomicAdd(&cur[lc], 1);                  // LDS atomic
        csr_row[pos] = (int)(v & 0x1FFFFu);                // ~130KB window -> L2
    }
}

// ---------------- layer 1 GEMM: hs = (x @ W1) * dinv  (stride-16, zero-padded) ----

__global__ void gemm1_kernel(const float* __restrict__ x, const float* __restrict__ W,
                             const float* __restrict__ dinv, float* __restrict__ hs) {
    __shared__ float Wl[DD * HH];
    __shared__ float xs[16 * DD];
    int tid = threadIdx.x;
    for (int i = tid; i < DD * HH; i += 256) Wl[i] = W[i];
    size_t base = (size_t)blockIdx.x * 16 * DD;
    const float4* xv = (const float4*)(x + base);
    float4* xsv = (float4*)xs;
    xsv[tid]       = xv[tid];
    xsv[tid + 256] = xv[tid + 256];
    __syncthreads();
    int g = tid >> 4, f = tid & 15;
    int n = blockIdx.x * 16 + g;
    float val = 0.f;
    if (f < HH) {
        const float* xrow = xs + g * DD;
        float acc = 0.f;
#pragma unroll 8
        for (int k = 0; k < DD; ++k) acc += xrow[k] * Wl[k * HH + f];
        val = acc * dinv[n];
    }
    hs[((size_t)n << 4) + f] = val;
}

// ---------------- mid layers: in = relu(agg + b), hs' = (in @ W) * dinv ----------

__global__ void gemm_mid_kernel(const float* __restrict__ agg_in, const float* __restrict__ bias,
                                const float* __restrict__ W, const float* __restrict__ dinv,
                                float* __restrict__ hs) {
    __shared__ float Wl[HH * HH];
    __shared__ float s_in[256];          // 16 nodes x stride 16
    int tid = threadIdx.x;
    if (tid < HH * HH) Wl[tid] = W[tid];
    int n0 = blockIdx.x * 16;
    int g = tid >> 4, f = tid & 15;
    if (f < HH) {
        float v = agg_in[((size_t)(n0 + g) << 4) + f] + bias[f];
        s_in[tid] = v > 0.f ? v : 0.f;
    }
    __syncthreads();
    int n = n0 + g;
    float val = 0.f;
    if (f < HH) {
        const float* in = s_in + g * 16;
        float acc = 0.f;
#pragma unroll
        for (int k = 0; k < HH; ++k) acc += in[k] * Wl[k * HH + f];
        val = acc * dinv[n];
    }
    hs[((size_t)n << 4) + f] = val;
}

// ---------------- gather aggregation: agg[c] = dinv[c]*(hs[c] + sum hs[row]) -----
// One wave per node; 4 lanes x float4 per edge -> 16 edges in flight per wave.

__device__ inline float4 shfl_down4(float4 v, int off) {
    v.x = __shfl_down(v.x, off, 64);
    v.y = __shfl_down(v.y, off, 64);
    v.z = __shfl_down(v.z, off, 64);
    v.w = __shfl_down(v.w, off, 64);
    return v;
}

__global__ void aggregate_kernel(const int* __restrict__ rowptr, const int* __restrict__ csr_row,
                                 const float* __restrict__ dinv, const float* __restrict__ hs,
                                 float* __restrict__ agg, int N) {
    int wave = (blockIdx.x * 256 + threadIdx.x) >> 6;
    int lane = threadIdx.x & 63;
    if (wave >= N) return;
    int c = wave;
    int s = rowptr[c], epe = rowptr[c + 1];
    int q = lane & 3, eg = lane >> 2;
    const float4* hs4 = (const float4*)hs;
    float4 acc = make_float4(0.f, 0.f, 0.f, 0.f);
    for (int e = s + eg; e < epe; e += 16) {
        int r = csr_row[e];
        float4 v = hs4[((size_t)r << 2) + q];
        acc.x += v.x; acc.y += v.y; acc.z += v.z; acc.w += v.w;
    }
#define RED4(off) { float4 t_ = shfl_down4(acc, off); \
                    acc.x += t_.x; acc.y += t_.y; acc.z += t_.z; acc.w += t_.w; }
    RED4(32) RED4(16) RED4(8) RED4(4)
#undef RED4
    if (lane < 4) {
        float d = dinv[c];
        float4 self = hs4[((size_t)c << 2) + lane];
        float4 o;
        o.x = d * (acc.x + self.x);
        o.y = d * (acc.y + self.y);
        o.z = d * (acc.z + self.z);
        o.w = d * (acc.w + self.w);
        ((float4*)agg)[((size_t)c << 2) + lane] = o;
    }
}

// ---------------- output GEMM: out = relu(agg + b3) @ Wc + bc ----------------

__global__ void gemm_out_kernel(const float* __restrict__ agg_in, const float* __restrict__ bias,
                                const float* __restrict__ Wc, const float* __restrict__ bc,
                                float* __restrict__ out) {
    __shared__ float Wl[HH * DD];
    __shared__ float s_in[32];
    int tid = threadIdx.x;
    for (int i = tid; i < HH * DD; i += 256) Wl[i] = Wc[i];
    int n0 = blockIdx.x * 2;
    if (tid < 32) {
        int gg = tid >> 4, ff = tid & 15;
        float v = (ff < HH) ? agg_in[((size_t)(n0 + gg) << 4) + ff] + bias[ff] : 0.f;
        s_in[tid] = v > 0.f ? v : 0.f;
    }
    __syncthreads();
    int g = tid >> 7, f = tid & 127;
    int n = n0 + g;
    const float* in = s_in + g * 16;
    float acc = bc[f];
#pragma unroll
    for (int k = 0; k < HH; ++k) acc += in[k] * Wl[k * DD + f];
    out[(size_t)n * DD + f] = acc;
}

// ---------------- launch ----------------

extern "C" void kernel_launch(void* const* d_in, const int* in_sizes, int n_in,
                              void* d_out, int out_size, void* d_ws, size_t ws_size,
                              hipStream_t stream) {
    const float* x  = (const float*)d_in[0];
    const int*   ei = (const int*)d_in[1];
    const float* W1 = (const float*)d_in[2];
    const float* b1 = (const float*)d_in[3];
    const float* W2 = (const float*)d_in[4];
    const float* b2 = (const float*)d_in[5];
    const float* W3 = (const float*)d_in[6];
    const float* b3 = (const float*)d_in[7];
    const float* Wc = (const float*)d_in[8];
    const float* bc = (const float*)d_in[9];
    float* out = (float*)d_out;

    int N = in_sizes[0] / DD;   // 100000
    int E = in_sizes[1] / 2;    // 6400000
    const int* row = ei;        // edge_index[0] = source
    const int* col = ei + E;    // edge_index[1] = target

    char* ws = (char*)d_ws;
    size_t off = 0;
    auto alloc = [&](size_t bytes) {
        void* p = ws + off;
        off += (bytes + 255) & ~(size_t)255;
        return p;
    };
    float*    dinv    = (float*)   alloc((size_t)N * 4);
    int*      rowptr  = (int*)     alloc((size_t)(N + 1) * 4);
    int*      bcount  = (int*)     alloc((size_t)NBUCK * 4);
    int*      bbase   = (int*)     alloc((size_t)(NBUCK + 1) * 4);
    int*      gcur    = (int*)     alloc((size_t)BHALF * 4);
    int*      csr_row = (int*)     alloc((size_t)E * 4);            // 25.6 MB
    unsigned* tmpHalf = (unsigned*)alloc((size_t)3400000 * 4);      // 13.6 MB
    (void)ws_size; (void)n_in; (void)out_size;

    // hs/agg (stride-16, 6.4 MB each) alias tmpHalf — tmp is dead after last partB.
    float* hsBuf  = (float*)tmpHalf;
    float* aggBuf = hsBuf + (size_t)N * 16;

    int eblocks = (E + CHUNK - 1) / CHUNK;             // 1563

    // bucket counts + bases (replaces global-atomic degree + N-wide scan)
    hipMemsetAsync(bcount, 0, (size_t)NBUCK * 4, stream);
    bucket_count<<<eblocks, 256, 0, stream>>>(col, bcount, E);
    scan196<<<1, 256, 0, stream>>>(bcount, bbase, rowptr, N, E);

    // CSR build: two half-passes (bounds tmp workspace); partB emits rowptr+dinv
    for (int pass = 0; pass < 2; ++pass) {
        int b0 = pass * BHALF;
        int b1 = min(b0 + BHALF, NBUCK);
        init_gcur<<<1, 128, 0, stream>>>(bbase, gcur, b0, b1 - b0);
        partA<<<eblocks, 256, 0, stream>>>(row, col, gcur, tmpHalf, E, b0, b1);
        partB<<<b1 - b0, 1024, 0, stream>>>(bbase, tmpHalf, rowptr, dinv, csr_row, N, b0);
    }

    int nb16 = (N + 15) / 16;                          // 6250
    int agg_blocks = (N + 3) / 4;                      // one wave per node

    // layer 1
    gemm1_kernel<<<nb16, 256, 0, stream>>>(x, W1, dinv, hsBuf);
    aggregate_kernel<<<agg_blocks, 256, 0, stream>>>(rowptr, csr_row, dinv, hsBuf, aggBuf, N);
    // layer 2
    gemm_mid_kernel<<<nb16, 256, 0, stream>>>(aggBuf, b1, W2, dinv, hsBuf);
    aggregate_kernel<<<agg_blocks, 256, 0, stream>>>(rowptr, csr_row, dinv, hsBuf, aggBuf, N);
    // layer 3
    gemm_mid_kernel<<<nb16, 256, 0, stream>>>(aggBuf, b2, W3, dinv, hsBuf);
    aggregate_kernel<<<agg_blocks, 256, 0, stream>>>(rowptr, csr_row, dinv, hsBuf, aggBuf, N);
    // output
    gemm_out_kernel<<<(N + 1) / 2, 256, 0, stream>>>(aggBuf, b3, Wc, bc, out);
}

// Round 5
// 640.116 us; speedup vs baseline: 3.4951x; 1.0266x over previous
//
#include <hip/hip_runtime.h>

#define DD 128
#define HH 15
#define BSHIFT 9                 // 512 nodes per bucket
#define NBUCK 196                // ceil(100000 / 512)
#define CHUNK 4096               // edges per partA block

// ---------------- bucket histogram (LDS, no global scatter atomics) ----------------

__global__ void bucket_count(const int* __restrict__ col, int* __restrict__ bcount, int E) {
    __shared__ int h[NBUCK];
    int tid = threadIdx.x;
    for (int i = tid; i < NBUCK; i += 256) h[i] = 0;
    __syncthreads();
    int start = blockIdx.x * CHUNK;
    for (int k = 0; k < 16; ++k) {
        int e = start + k * 256 + tid;
        if (e < E) atomicAdd(&h[col[e] >> BSHIFT], 1);   // LDS atomic
    }
    __syncthreads();
    for (int i = tid; i < NBUCK; i += 256)
        if (h[i]) atomicAdd(&bcount[i], h[i]);           // ~196 global adds/block
}

// scan 196 bucket counts -> bbase[197]; also rowptr[N] = E
__global__ void scan196(const int* __restrict__ bcount, int* __restrict__ bbase,
                        int* __restrict__ rowptr, int N, int E) {
    __shared__ int sh[256];
    int t = threadIdx.x;
    int v = (t < NBUCK) ? bcount[t] : 0;
    sh[t] = v;
    __syncthreads();
    for (int off = 1; off < 256; off <<= 1) {
        int x = (t >= off) ? sh[t - off] : 0;
        __syncthreads();
        sh[t] += x;
        __syncthreads();
    }
    if (t < NBUCK) bbase[t] = sh[t] - v;   // exclusive
    if (t == 0) { bbase[NBUCK] = E; rowptr[N] = E; }
}

__global__ void init_gcur(const int* __restrict__ bbase, int* __restrict__ gcur,
                          int b0, int nb) {
    int i = threadIdx.x;
    if (i < nb) gcur[i] = bbase[b0 + i] - bbase[b0];   // offset within tmp
}

// ---------------- CSR build, phase A: LDS-staged bucket binning ----------------
// pack = row (17b) | local_col (9b) << 17

__global__ void partA(const int* __restrict__ row, const int* __restrict__ col,
                      int* __restrict__ gcur, unsigned* __restrict__ tmp,
                      int E, int b0, int b1) {
    __shared__ int histo[NBUCK];
    __shared__ int hbase[NBUCK];
    __shared__ int hscan[NBUCK];
    __shared__ int scanT[256];
    __shared__ int s_total;
    __shared__ unsigned staged[CHUNK];
    __shared__ int saddr[CHUNK];
    int tid = threadIdx.x;
    int start = blockIdx.x * CHUNK;
    int nb = b1 - b0;
    for (int i = tid; i < nb; i += 256) histo[i] = 0;
    __syncthreads();
    unsigned pk[16]; unsigned short lp[16]; unsigned char bk[16];
    for (int k = 0; k < 16; ++k) {
        int e = start + k * 256 + tid;
        bk[k] = 0xFF;
        if (e < E) {
            int cc = col[e];
            int b = cc >> BSHIFT;
            if (b >= b0 && b < b1) {
                int rr = row[e];
                pk[k] = (unsigned)rr | ((unsigned)(cc & ((1 << BSHIFT) - 1)) << 17);
                bk[k] = (unsigned char)(b - b0);
                lp[k] = (unsigned short)atomicAdd(&histo[b - b0], 1);
            }
        }
    }
    __syncthreads();
    int v = (tid < nb) ? histo[tid] : 0;
    scanT[tid] = v;
    __syncthreads();
    for (int off = 1; off < 256; off <<= 1) {
        int t2 = (tid >= off) ? scanT[tid - off] : 0;
        __syncthreads();
        scanT[tid] += t2;
        __syncthreads();
    }
    if (tid == 255) s_total = scanT[255];
    if (tid < nb) {
        hscan[tid] = scanT[tid] - v;                       // chunk-local exclusive
        if (v > 0) hbase[tid] = atomicAdd(&gcur[tid], v);  // reserve global run
    }
    __syncthreads();
    for (int k = 0; k < 16; ++k) {
        if (bk[k] != 0xFF) {
            int b = bk[k];
            int slot = hscan[b] + lp[k];
            staged[slot] = pk[k];
            saddr[slot]  = hbase[b] + lp[k];
        }
    }
    __syncthreads();
    int tot = s_total;
    for (int k = tid; k < tot; k += 256)
        tmp[saddr[k]] = staged[k];                         // bucket-contiguous runs
}

// ---------------- CSR build, phase B ----------------
// Per bucket: LDS degree histogram -> rowptr + dinv, then LDS-cursor scatter.

__global__ void partB(const int* __restrict__ bbase, const unsigned* __restrict__ tmp,
                      int* __restrict__ rowptr, float* __restrict__ dinv,
                      int* __restrict__ csr_row, int N, int b0) {
    __shared__ int hist[1 << BSHIFT];
    __shared__ int cur[1 << BSHIFT];
    int b = b0 + blockIdx.x;
    int node0 = b << BSHIFT;
    int nn = min(1 << BSHIFT, N - node0);
    int tid = threadIdx.x;
    for (int i = tid; i < (1 << BSHIFT); i += 1024) hist[i] = 0;
    __syncthreads();
    int base = bbase[b], end = bbase[b + 1];
    int lbase = bbase[b0];
    for (int e = base + tid; e < end; e += 1024)
        atomicAdd(&hist[tmp[e - lbase] >> 17], 1);         // LDS atomic
    __syncthreads();
    int d0 = (tid < (1 << BSHIFT)) ? hist[tid] : 0;
    for (int off = 1; off < (1 << BSHIFT); off <<= 1) {
        int x = 0;
        if (tid < (1 << BSHIFT) && tid >= off) x = hist[tid - off];
        __syncthreads();
        if (tid < (1 << BSHIFT)) hist[tid] += x;
        __syncthreads();
    }
    if (tid < (1 << BSHIFT)) {
        int excl = hist[tid] - d0;
        cur[tid] = base + excl;
        if (tid < nn) {
            rowptr[node0 + tid] = base + excl;
            dinv[node0 + tid] = 1.0f / sqrtf((float)(d0 + 1));   // +1 self-loop
        }
    }
    __syncthreads();
    for (int e = base + tid; e < end; e += 1024) {
        unsigned v = tmp[e - lbase];
        int lc = (int)(v >> 17);
        int pos = atomicAdd(&cur[lc], 1);                  // LDS atomic
        csr_row[pos] = (int)(v & 0x1FFFFu);                // ~130KB window -> L2
    }
}

// ---------------- layer 1 GEMM: hs = (x @ W1) * dinv  (two 8-float planes) --------

__global__ void gemm1_kernel(const float* __restrict__ x, const float* __restrict__ W,
                             const float* __restrict__ dinv,
                             float* __restrict__ hsA, float* __restrict__ hsB) {
    __shared__ float Wl[DD * HH];
    __shared__ float xs[16 * DD];
    int tid = threadIdx.x;
    for (int i = tid; i < DD * HH; i += 256) Wl[i] = W[i];
    size_t base = (size_t)blockIdx.x * 16 * DD;
    const float4* xv = (const float4*)(x + base);
    float4* xsv = (float4*)xs;
    xsv[tid]       = xv[tid];
    xsv[tid + 256] = xv[tid + 256];
    __syncthreads();
    int g = tid >> 4, f = tid & 15;
    int n = blockIdx.x * 16 + g;
    float val = 0.f;
    if (f < HH) {
        const float* xrow = xs + g * DD;
        float acc = 0.f;
#pragma unroll 8
        for (int k = 0; k < DD; ++k) acc += xrow[k] * Wl[k * HH + f];
        val = acc * dinv[n];
    }
    float* plane = (f < 8) ? hsA : hsB;
    plane[((size_t)n << 3) + (f & 7)] = val;
}

// ---------------- mid layers: in = relu(agg + b), hs' = (in @ W) * dinv ----------

__global__ void gemm_mid_kernel(const float* __restrict__ aggA, const float* __restrict__ aggB,
                                const float* __restrict__ bias,
                                const float* __restrict__ W, const float* __restrict__ dinv,
                                float* __restrict__ hsA, float* __restrict__ hsB) {
    __shared__ float Wl[HH * HH];
    __shared__ float s_in[256];          // 16 nodes x stride 16
    int tid = threadIdx.x;
    if (tid < HH * HH) Wl[tid] = W[tid];
    int n0 = blockIdx.x * 16;
    int g = tid >> 4, f = tid & 15;
    int n = n0 + g;
    if (f < HH) {
        const float* pl = (f < 8) ? aggA : aggB;
        float v = pl[((size_t)n << 3) + (f & 7)] + bias[f];
        s_in[tid] = v > 0.f ? v : 0.f;
    }
    __syncthreads();
    float val = 0.f;
    if (f < HH) {
        const float* in = s_in + g * 16;
        float acc = 0.f;
#pragma unroll
        for (int k = 0; k < HH; ++k) acc += in[k] * Wl[k * HH + f];
        val = acc * dinv[n];
    }
    float* plane = (f < 8) ? hsA : hsB;
    plane[((size_t)n << 3) + (f & 7)] = val;
}

// ---------------- gather aggregation, one 32B plane per pass -----------------
// One wave per node; 2 lanes x float4 per edge -> 32 edges in flight per wave.
// Plane footprint 3.2 MB -> L2-resident per XCD.

__device__ inline float4 shfl_down4(float4 v, int off) {
    v.x = __shfl_down(v.x, off, 64);
    v.y = __shfl_down(v.y, off, 64);
    v.z = __shfl_down(v.z, off, 64);
    v.w = __shfl_down(v.w, off, 64);
    return v;
}

__global__ void aggregate_kernel(const int* __restrict__ rowptr, const int* __restrict__ csr_row,
                                 const float* __restrict__ dinv, const float* __restrict__ hsP,
                                 float* __restrict__ aggP, int N) {
    int wave = (blockIdx.x * 256 + threadIdx.x) >> 6;
    int lane = threadIdx.x & 63;
    if (wave >= N) return;
    int c = wave;
    int s = rowptr[c], epe = rowptr[c + 1];
    int q = lane & 1, eg = lane >> 1;
    const float4* h4 = (const float4*)hsP;
    float4 acc = make_float4(0.f, 0.f, 0.f, 0.f);
    for (int e = s + eg; e < epe; e += 32) {
        int r = csr_row[e];
        float4 v = h4[((size_t)r << 1) + q];
        acc.x += v.x; acc.y += v.y; acc.z += v.z; acc.w += v.w;
    }
#define RED4(off) { float4 t_ = shfl_down4(acc, off); \
                    acc.x += t_.x; acc.y += t_.y; acc.z += t_.z; acc.w += t_.w; }
    RED4(32) RED4(16) RED4(8) RED4(4) RED4(2)   // even offsets preserve q-parity
#undef RED4
    if (lane < 2) {
        float d = dinv[c];
        float4 self = h4[((size_t)c << 1) + lane];
        float4 o;
        o.x = d * (acc.x + self.x);
        o.y = d * (acc.y + self.y);
        o.z = d * (acc.z + self.z);
        o.w = d * (acc.w + self.w);
        ((float4*)aggP)[((size_t)c << 1) + lane] = o;
    }
}

// ---------------- output GEMM: out = relu(agg + b3) @ Wc + bc ----------------

__global__ void gemm_out_kernel(const float* __restrict__ aggA, const float* __restrict__ aggB,
                                const float* __restrict__ bias,
                                const float* __restrict__ Wc, const float* __restrict__ bc,
                                float* __restrict__ out) {
    __shared__ float Wl[HH * DD];
    __shared__ float s_in[32];
    int tid = threadIdx.x;
    for (int i = tid; i < HH * DD; i += 256) Wl[i] = Wc[i];
    int n0 = blockIdx.x * 2;
    if (tid < 32) {
        int gg = tid >> 4, ff = tid & 15;
        float v = 0.f;
        if (ff < HH) {
            const float* pl = (ff < 8) ? aggA : aggB;
            v = pl[((size_t)(n0 + gg) << 3) + (ff & 7)] + bias[ff];
        }
        s_in[tid] = v > 0.f ? v : 0.f;
    }
    __syncthreads();
    int g = tid >> 7, f = tid & 127;
    int n = n0 + g;
    const float* in = s_in + g * 16;
    float acc = bc[f];
#pragma unroll
    for (int k = 0; k < HH; ++k) acc += in[k] * Wl[k * DD + f];
    out[(size_t)n * DD + f] = acc;
}

// ---------------- launch ----------------

extern "C" void kernel_launch(void* const* d_in, const int* in_sizes, int n_in,
                              void* d_out, int out_size, void* d_ws, size_t ws_size,
                              hipStream_t stream) {
    const float* x  = (const float*)d_in[0];
    const int*   ei = (const int*)d_in[1];
    const float* W1 = (const float*)d_in[2];
    const float* b1 = (const float*)d_in[3];
    const float* W2 = (const float*)d_in[4];
    const float* b2 = (const float*)d_in[5];
    const float* W3 = (const float*)d_in[6];
    const float* b3 = (const float*)d_in[7];
    const float* Wc = (const float*)d_in[8];
    const float* bc = (const float*)d_in[9];
    float* out = (float*)d_out;

    int N = in_sizes[0] / DD;   // 100000
    int E = in_sizes[1] / 2;    // 6400000
    const int* row = ei;        // edge_index[0] = source
    const int* col = ei + E;    // edge_index[1] = target

    char* ws = (char*)d_ws;
    size_t off = 0;
    auto alloc = [&](size_t bytes) {
        void* p = ws + off;
        off += (bytes + 255) & ~(size_t)255;
        return p;
    };
    float*    dinv    = (float*)   alloc((size_t)N * 4);
    int*      rowptr  = (int*)     alloc((size_t)(N + 1) * 4);
    int*      bcount  = (int*)     alloc((size_t)NBUCK * 4);
    int*      bbase   = (int*)     alloc((size_t)(NBUCK + 1) * 4);
    int*      gcur    = (int*)     alloc((size_t)NBUCK * 4);
    int*      csr_row = (int*)     alloc((size_t)E * 4);            // 25.6 MB
    (void)n_in; (void)out_size;

    // tmp: prefer full-E single pass (saves one 51.2 MB edge-list read);
    // fall back to half-size two-pass if workspace is tight.
    size_t need1 = off + ((size_t)E * 4 + 255);
    int npass; size_t tmpElems;
    if (ws_size >= need1 + 4096) { npass = 1; tmpElems = (size_t)E; }
    else                        { npass = 2; tmpElems = 3400000; }
    unsigned* tmp = (unsigned*)alloc(tmpElems * 4);

    // hs/agg planes (N x 8 floats = 3.2 MB each) alias tmp — tmp dead after partB.
    float* hsA  = (float*)tmp;
    float* hsB  = hsA + (size_t)N * 8;
    float* aggA = hsB + (size_t)N * 8;
    float* aggB = aggA + (size_t)N * 8;

    int eblocks = (E + CHUNK - 1) / CHUNK;             // 1563

    // bucket counts + bases
    hipMemsetAsync(bcount, 0, (size_t)NBUCK * 4, stream);
    bucket_count<<<eblocks, 256, 0, stream>>>(col, bcount, E);
    scan196<<<1, 256, 0, stream>>>(bcount, bbase, rowptr, N, E);

    // CSR build; partB emits rowptr + dinv
    int bper = (NBUCK + npass - 1) / npass;
    for (int pass = 0; pass < npass; ++pass) {
        int b0 = pass * bper;
        int b1 = min(b0 + bper, NBUCK);
        init_gcur<<<1, 256, 0, stream>>>(bbase, gcur, b0, b1 - b0);
        partA<<<eblocks, 256, 0, stream>>>(row, col, gcur, tmp, E, b0, b1);
        partB<<<b1 - b0, 1024, 0, stream>>>(bbase, tmp, rowptr, dinv, csr_row, N, b0);
    }

    int nb16 = (N + 15) / 16;                          // 6250
    int agg_blocks = (N + 3) / 4;                      // one wave per node

    // layer 1
    gemm1_kernel<<<nb16, 256, 0, stream>>>(x, W1, dinv, hsA, hsB);
    aggregate_kernel<<<agg_blocks, 256, 0, stream>>>(rowptr, csr_row, dinv, hsA, aggA, N);
    aggregate_kernel<<<agg_blocks, 256, 0, stream>>>(rowptr, csr_row, dinv, hsB, aggB, N);
    // layer 2
    gemm_mid_kernel<<<nb16, 256, 0, stream>>>(aggA, aggB, b1, W2, dinv, hsA, hsB);
    aggregate_kernel<<<agg_blocks, 256, 0, stream>>>(rowptr, csr_row, dinv, hsA, aggA, N);
    aggregate_kernel<<<agg_blocks, 256, 0, stream>>>(rowptr, csr_row, dinv, hsB, aggB, N);
    // layer 3
    gemm_mid_kernel<<<nb16, 256, 0, stream>>>(aggA, aggB, b2, W3, dinv, hsA, hsB);
    aggregate_kernel<<<agg_blocks, 256, 0, stream>>>(rowptr, csr_row, dinv, hsA, aggA, N);
    aggregate_kernel<<<agg_blocks, 256, 0, stream>>>(rowptr, csr_row, dinv, hsB, aggB, N);
    // output
    gemm_out_kernel<<<(N + 1) / 2, 256, 0, stream>>>(aggA, aggB, b3, Wc, bc, out);
}